// Round 10
// baseline (21173.105 us; speedup 1.0000x reference)
//
#include <hip/hip_runtime.h>
#include <hip/hip_bf16.h>
#include <cstddef>

#define B     32
#define TENC  200
#define E     512
#define D     1024
#define P     256
#define M     80
#define TDEC  600
#define A     128
#define KC    31
#define LF    32

typedef __attribute__((ext_vector_type(8))) short short8;
typedef __attribute__((ext_vector_type(4))) float float4v;
typedef __attribute__((ext_vector_type(2))) unsigned int uint2v;
typedef unsigned short u16;

// output offsets (floats)
#define SPEC_OFF  0
#define STOP_OFF  ((size_t)B * TDEC * M)
#define ALIGN_OFF (STOP_OFF + (size_t)B * TDEC)

// ---------------- workspace layout (float units) ----------------
constexpr size_t OFF_PM   = 0;                    // fp32 [b][t][a]   819200
constexpr size_t OFF_PREB = 819200;               // bf16 fragment-major [t][8192] 2457600 f
constexpr size_t OFF_KPK  = 3276800;              // bf16 packed keff 8192 -> 4096 f
constexpr size_t OFF_WQB  = 3280896;              // bf16 Wq 131072 -> 65536 f
constexpr size_t OFF_FWB  = 3346432;              // bf16 frame/stop W 81*1536 -> 62208 f
constexpr size_t OFF_ST   = 3408640;
// state region (zeroed each call), float offsets relative to OFF_ST:
constexpr size_t ST_HAB0 = 0;       // bf16 fragment-major 32768 u16 -> 16384 f
constexpr size_t ST_HAB1 = 16384;
constexpr size_t ST_HGB0 = 32768;
constexpr size_t ST_HGB1 = 49152;
constexpr size_t ST_CTXB = 65536;   // bf16 fragment-major 16384 u16 -> 8192 f
constexpr size_t ST_CTXF = 73728;   // fp32 2 x [b][512] -> 32768 f
constexpr size_t ST_HGF  = 106496;  // fp32 [b][1024] -> 32768 f
constexpr size_t ST_BARS = 139264;  // 1344 f barrier counters + release lines
constexpr size_t ST_EPS  = 140608;  // fp32 32 x 256 energy exchange = 8192 f
constexpr size_t ST_GC   = 148800;  // 32 group counters x 32 f = 1024 f
constexpr size_t N_STATE = 149824;

// ---------------- LDS layout (bytes) ----------------
constexpr int LDS_ATTW = 0;          // 56*512*2  = 57344
constexpr int LDS_GENW = 57344;      // 80*512*2  = 81920
constexpr int LDS_SC   = 139264;     // 5184 floats scratch (20736 B)
constexpr int LDS_SP   = 160000;     // 232 f padded wprev
constexpr int LDS_SCM  = 160928;     // 232 f padded wcum
constexpr int LDS_CA   = 161856;     // 128 f
constexpr int LDS_CG   = 162368;     // 128 f
constexpr int SMEM_BYTES = 162880;   // <= 163840

struct Params {
  const float* enc; const int* lens;
  const float *att_Wih, *att_Whh, *att_b, *gen_Wih, *gen_Whh, *gen_b;
  const float *v_att, *b_att, *frame_b, *stop_b;
  const float *pm;
  const u16 *preB, *kpk, *wqb, *fwb;
  u16 *hAb0, *hAb1, *hGb0, *hGb1, *ctxb;
  float *ctxf, *hGf;
  unsigned* bars;
  float* eps;
  unsigned* gc;
  float* out;
};

__device__ __forceinline__ float sigmoidf(float x) { return 1.0f / (1.0f + __expf(-x)); }
__device__ __forceinline__ float tanhfast(float x) {
  float ax = fabsf(x);
  float e = __expf(2.0f * ax);
  float t = 1.0f - 2.0f / (e + 1.0f);
  return copysignf(t, x);
}
__device__ __forceinline__ u16 f2bf(float x) {
  __hip_bfloat16 h = __float2bfloat16(x);
  return __builtin_bit_cast(u16, h);
}
__device__ __forceinline__ float bf2f(u16 u) {
  unsigned v = ((unsigned)u) << 16;
  return __builtin_bit_cast(float, v);
}

// ---- MALL-coherent access helpers (bypass non-coherent per-XCD L2) ----
#define LDC(r, p) asm volatile("global_load_dwordx4 %0, %1, off sc0 sc1" : "=v"(r) : "v"(p))
// plain cached load (immutable data during the persistent kernel):
#define LDP(r, p) asm volatile("global_load_dwordx4 %0, %1, off" : "=v"(r) : "v"(p))

__device__ __forceinline__ float4v ldc1(const void* p) {
  float4v r;
  LDC(r, p);
  asm volatile("s_waitcnt vmcnt(0)" : "+v"(r) :: "memory");
  return r;
}
__device__ __forceinline__ float ldc_f32(const float* pf) {
  float r;
  asm volatile("global_load_dword %0, %1, off sc0 sc1" : "=v"(r) : "v"(pf));
  asm volatile("s_waitcnt vmcnt(0)" : "+v"(r) :: "memory");
  return r;
}
__device__ __forceinline__ void stc_f32(float* p, float v) {
  asm volatile("global_store_dword %0, %1, off sc0 sc1" :: "v"(p), "v"(v) : "memory");
}
__device__ __forceinline__ void stc_u16(u16* p, u16 v) {
  unsigned vv = v;
  asm volatile("global_store_short %0, %1, off sc0 sc1" :: "v"(p), "v"(vv) : "memory");
}
__device__ __forceinline__ void stc_8B(void* p, uint2v v) {
  asm volatile("global_store_dwordx2 %0, %1, off sc0 sc1" :: "v"(p), "v"(v) : "memory");
}
__device__ __forceinline__ void stc_16B(void* p, float4v v) {
  asm volatile("global_store_dwordx4 %0, %1, off sc0 sc1" :: "v"(p), "v"(v) : "memory");
}

// ---------------------------------------------------------------------------
// grid barrier WITHOUT agent-scope fences.  Arrival: 16 group counters +
// central.  Release: 16 per-group lines (16 pollers/line).
__device__ __forceinline__ void gbar(unsigned* bars, int ep) {
  __syncthreads();
  if (threadIdx.x == 0) {
    const int grp = blockIdx.x >> 4;          // 16 groups x 16 blocks
    unsigned old = atomicAdd(bars + (grp << 5), 1u);
    if (old + 1u == (unsigned)ep * 16u) {
      unsigned cold = atomicAdd(bars + 768, 1u);
      if (cold + 1u == (unsigned)ep * 16u) {
        #pragma unroll
        for (int g2 = 0; g2 < 16; ++g2)
          __hip_atomic_store(bars + 800 + (g2 << 5), (unsigned)ep,
                             __ATOMIC_RELAXED, __HIP_MEMORY_SCOPE_AGENT);
      }
    }
    while (__hip_atomic_load(bars + 800 + (grp << 5), __ATOMIC_RELAXED,
                             __HIP_MEMORY_SCOPE_AGENT) < (unsigned)ep)
      __builtin_amdgcn_s_sleep(2);
  }
  __syncthreads();
}

// ---------------------------------------------------------------------------
// Fragment-major layouts (u16 offsets), global k-chunk index kappa:
//   off = kappa*1024 + (m>>4)*512 + lane*8   (consumer wave reads 1KB bursts)

// NOTE: __launch_bounds__(512) NOT (512,2): grid is exactly 256 blocks on
// 256 CUs (1 block/CU resident), so min-waves=2 only capped the allocator
// at 128 VGPRs and forced the round-9 hoisted state to spill to scratch
// (+634 MB HBM traffic).  2 waves/SIMD permits 256 VGPRs.
__global__ void __launch_bounds__(512) persist_kernel(Params p) {
  extern __shared__ char smem[];
  __hip_bfloat16* attw = (__hip_bfloat16*)(smem + LDS_ATTW);
  __hip_bfloat16* genw = (__hip_bfloat16*)(smem + LDS_GENW);
  float* sc   = (float*)(smem + LDS_SC);
  float* sp   = (float*)(smem + LDS_SP);
  float* scm  = (float*)(smem + LDS_SCM);
  float* cAl  = (float*)(smem + LDS_CA);
  float* cGl  = (float*)(smem + LDS_CG);
  // PA-phase scratch sublayout (time-multiplexed):
  float* hq    = sc;                       // [0..1056) padded 4 x 264 gather
  float* qpart = sc + 1088;                // [1088..1600)
  u16*   Abuf  = (u16*)(smem + LDS_SC + 6784);   // floats [1696..2208), conv only
  float* cpart = sc + 2048;                // ctx partials [2048..2560) (conv-dead)
  float* csum  = sc + 2560;                // ctx sums [2560..2624)
  float* query = sc + 2624;                // [2624..2752)
  float* red   = sc + 2752;                // [2752..2760)
  float* epart = sc + 3360;                // [3360..4960)
  float* e_w   = sc + 4960;                // [4960..5160)
  float* Xf    = sc;                       // frame proto [0..1536) (gather/query dead)
  float* hstg  = sc + 4200;                // PG epilogue hn stage (PG-phase only)

  const int tid  = threadIdx.x;
  const int blk  = blockIdx.x;
  const int lane = tid & 63;
  const int wv   = tid >> 6;
  const int b    = blk >> 3;   // group = batch
  const int k    = blk & 7;    // slice within group
  int ep = 0;

  // ============ prolog: pack weight slices into LDS (unchanged scheme) ============
  for (int idx = tid; idx < 56 * 512; idx += 512) {
    int k0 = idx >> 9, e = idx & 511, ln = e >> 3, j = e & 7, r = ln & 15;
    int row = (r & 3) * D + blk * 4 + (r >> 2);
    int kq8 = ((ln >> 4) << 3) + j;
    int w = k0 / 14, s = k0 - w * 14;
    float v;
    if (s < 2) {
      int kk = (w * 2 + s) * 32 + kq8;
      v = p.att_Wih[(size_t)row * 768 + kk];
    } else if (s < 10) {
      int kk = (w * 8 + (s - 2)) * 32 + kq8;
      v = p.att_Whh[(size_t)row * D + kk];
    } else {
      int kk = 256 + (w * 4 + (s - 10)) * 32 + kq8;
      v = p.att_Wih[(size_t)row * 768 + kk];
    }
    attw[idx] = __float2bfloat16(v);
  }
  for (int idx = tid; idx < 80 * 512; idx += 512) {
    int k0 = idx >> 9, e = idx & 511, ln = e >> 3, j = e & 7, r = ln & 15;
    int row = (r & 3) * D + blk * 4 + (r >> 2);
    int kq8 = ((ln >> 4) << 3) + j;
    int w = k0 / 20, s = k0 - w * 20;
    float v;
    if (s < 8) {
      int kk = (w * 8 + s) * 32 + kq8;
      v = p.gen_Wih[(size_t)row * 1536 + kk];
    } else if (s < 16) {
      int kk = (w * 8 + (s - 8)) * 32 + kq8;
      v = p.gen_Whh[(size_t)row * D + kk];
    } else {
      int kk = 1024 + (w * 4 + (s - 16)) * 32 + kq8;
      v = p.gen_Wih[(size_t)row * 1536 + kk];
    }
    genw[idx] = __float2bfloat16(v);
  }
  if (tid < 128) { cAl[tid] = 0.f; cGl[tid] = 0.f; }
  for (int i = tid; i < 232; i += 512) { sp[i] = 0.f; scm[i] = 0.f; }
  __syncthreads();

  // per-thread constant geometry
  const int mt  = wv & 1, kqi = wv >> 1;
  const size_t offPreF = (size_t)kqi * 2048 + (size_t)mt * 512 + (size_t)lane * 8;
  const size_t offHF   = (size_t)kqi * 8192 + (size_t)mt * 512 + (size_t)lane * 8;
  const size_t offCF   = (size_t)kqi * 4096 + (size_t)mt * 512 + (size_t)lane * 8;
  const __hip_bfloat16* awp = attw + (size_t)(kqi * 14) * 512 + (size_t)lane * 8;
  const __hip_bfloat16* gwp = genw + (size_t)(kqi * 20) * 512 + (size_t)lane * 8;
  const int kqiB = blk >> 6, rB = (blk >> 3) & 7, lhB = (blk >> 1) & 3, j0B = (blk & 1) * 4;

  // ============ hoisted t-invariant constants (registers) ============
  const int cl_h = lane & 15;
  const int kq8c = (lane >> 4) << 3;
  const int tile0 = k, tile1 = k + 8;
  const int ntile = (k <= 4) ? 2 : 1;
  // conv B-fragments (kpk constant)
  const short8 bfrag0 = *(const short8*)(p.kpk + ((size_t)(0 * 8 + wv) * 64 + lane) * 8);
  const short8 bfrag1 = *(const short8*)(p.kpk + ((size_t)(1 * 8 + wv) * 64 + lane) * 8);
  // energies: pm terms + v_att
  float pmh[8];
  {
    const int a = wv * 16 + cl_h;
    #pragma unroll
    for (int i = 0; i < 4; ++i) {
      int tt0 = tile0 * 16 + ((lane >> 4) << 2) + i;
      pmh[i] = (tt0 < 200) ? p.pm[((size_t)b * TENC + tt0) * A + a] : 0.f;
      int tt1 = tile1 * 16 + ((lane >> 4) << 2) + i;
      pmh[4 + i] = (ntile == 2 && tt1 < 200) ? p.pm[((size_t)b * TENC + tt1) * A + a] : 0.f;
    }
  }
  const float vvh = p.v_att[wv * 16 + cl_h];
  const float qbias = (tid < 128) ? p.b_att[tid] : 0.f;
  const int lenb = p.lens[b];
  // frame rows owned by this (block, wave): row0 always; row1 conditionally
  const int row0 = k * 10 + wv;
  const bool has1 = (wv < 2) || (k == 0 && wv == 2);
  const int row1 = (k == 0 && wv == 2) ? 80 : (k * 10 + wv + 8);
  short8 fw0a, fw0b, fw0c, fw1a, fw1b, fw1c;
  float fbias0, fbias1 = 0.f;
  {
    const u16* w0 = p.fwb + (size_t)row0 * 1536 + lane;
    #pragma unroll
    for (int i = 0; i < 8; ++i) {
      ((u16*)&fw0a)[i] = w0[(size_t)i * 64];
      ((u16*)&fw0b)[i] = w0[(size_t)(i + 8) * 64];
      ((u16*)&fw0c)[i] = w0[(size_t)(i + 16) * 64];
    }
    fbias0 = p.frame_b[row0];
    if (has1) {
      const u16* w1 = p.fwb + (size_t)row1 * 1536 + lane;
      #pragma unroll
      for (int i = 0; i < 8; ++i) {
        ((u16*)&fw1a)[i] = w1[(size_t)i * 64];
        ((u16*)&fw1b)[i] = w1[(size_t)(i + 8) * 64];
        ((u16*)&fw1c)[i] = w1[(size_t)(i + 16) * 64];
      }
      fbias1 = (row1 < M) ? p.frame_b[row1] : p.stop_b[0];
    }
  }
  // PG gate biases
  float biash[4] = {0.f, 0.f, 0.f, 0.f};
  if (tid < 256) {
    const int dj_l = (tid >> 5) & 3;
    const int dj = blk * 4 + dj_l;
    const float* bias = ((tid >> 7) == 0) ? p.att_b : p.gen_b;
    #pragma unroll
    for (int g4i = 0; g4i < 4; ++g4i) biash[g4i] = bias[g4i * D + dj];
  }

  // group-distributed frame/stop projection, hoisted weights
  auto frame_do = [&](int ft) {
    const int slot = ft & 1;
    if (tid < 384) {
      const float* src = (tid < 256)
          ? (p.hGf + (size_t)b * 1024 + (size_t)tid * 4)
          : (p.ctxf + (size_t)slot * (E * B) + (size_t)b * 512 + (size_t)(tid - 256) * 4);
      float4v v = ldc1(src);
      *(float4v*)(Xf + tid * 4) = v;
    }
    __syncthreads();
    {
      float acc = 0.f, acc2 = 0.f;
      #pragma unroll
      for (int i = 0; i < 8; ++i) acc  += bf2f(((const u16*)&fw0a)[i]) * Xf[lane + i * 64];
      #pragma unroll
      for (int i = 0; i < 8; ++i) acc2 += bf2f(((const u16*)&fw0b)[i]) * Xf[lane + (i + 8) * 64];
      #pragma unroll
      for (int i = 0; i < 8; ++i) acc  += bf2f(((const u16*)&fw0c)[i]) * Xf[lane + (i + 16) * 64];
      acc += acc2;
      for (int o = 32; o > 0; o >>= 1) acc += __shfl_down(acc, o, 64);
      if (lane == 0)
        p.out[SPEC_OFF + (size_t)b * TDEC * M + (size_t)ft * M + row0] = acc + fbias0;
    }
    if (has1) {
      float acc = 0.f, acc2 = 0.f;
      #pragma unroll
      for (int i = 0; i < 8; ++i) acc  += bf2f(((const u16*)&fw1a)[i]) * Xf[lane + i * 64];
      #pragma unroll
      for (int i = 0; i < 8; ++i) acc2 += bf2f(((const u16*)&fw1b)[i]) * Xf[lane + (i + 8) * 64];
      #pragma unroll
      for (int i = 0; i < 8; ++i) acc  += bf2f(((const u16*)&fw1c)[i]) * Xf[lane + (i + 16) * 64];
      acc += acc2;
      for (int o = 32; o > 0; o >>= 1) acc += __shfl_down(acc, o, 64);
      if (lane == 0) {
        if (row1 < M) p.out[SPEC_OFF + (size_t)b * TDEC * M + (size_t)ft * M + row1] = acc + fbias1;
        else          p.out[STOP_OFF + (size_t)b * TDEC + ft] = acc + fbias1;
      }
    }
    __syncthreads();
  };

#define MFA(i, reg) accA = __builtin_amdgcn_mfma_f32_16x16x32_bf16( \
    __builtin_bit_cast(short8, reg), *(const short8*)(awp + (size_t)(i) * 512), accA, 0, 0, 0)
#define MFG(i, reg) accG = __builtin_amdgcn_mfma_f32_16x16x32_bf16( \
    __builtin_bit_cast(short8, reg), *(const short8*)(gwp + (size_t)(i) * 512), accG, 0, 0, 0)

#define ISSUE18() do { \
    const u16* _pr = p.preB + (size_t)tp1 * (B * P) + offPreF; \
    const u16* _ha = hAcur + offHF; \
    const u16* _hg = hGprev + offHF; \
    LDP(e0, _pr); LDP(e1, _pr + 1024); \
    LDC(e2, _ha); LDC(e3, _ha + 1024); LDC(e4, _ha + 2048); LDC(e5, _ha + 3072); \
    LDC(e6, _ha + 4096); LDC(e7, _ha + 5120); LDC(e8, _ha + 6144); LDC(e9, _ha + 7168); \
    LDC(e10, _hg); LDC(e11, _hg + 1024); LDC(e12, _hg + 2048); LDC(e13, _hg + 3072); \
    LDC(e14, _hg + 4096); LDC(e15, _hg + 5120); LDC(e16, _hg + 6144); LDC(e17, _hg + 7168); \
  } while (0)

  // ============ pre-phase: att gates for t=0 (ctx=0, hA=0 => only preB term) ============
  {
    const u16* _pr = p.preB + offPreF;
    float4v e0, e1;
    LDP(e0, _pr); LDP(e1, _pr + 1024);
    asm volatile("s_waitcnt vmcnt(0)" : "+v"(e0), "+v"(e1) :: "memory");
    float4v accA = {0.f, 0.f, 0.f, 0.f};
    MFA(0, e0); MFA(1, e1);
    float* r = sc + ((((0 * 2 + mt) * 4 + kqi) * 64 + lane) << 2);
    r[0] = accA[0]; r[1] = accA[1]; r[2] = accA[2]; r[3] = accA[3];
    __syncthreads();
    if (tid < 128) {
      int dj_l = (tid >> 5) & 3, mm = tid & 31;
      int dj = blk * 4 + dj_l;
      int mt2 = mm >> 4, m2 = mm & 15;
      float g4[4];
      #pragma unroll
      for (int gate = 0; gate < 4; ++gate) {
        int ln = ((m2 >> 2) << 4) | (dj_l * 4 + gate);
        int rg = m2 & 3;
        float s = 0.f;
        #pragma unroll
        for (int kk = 0; kk < 4; ++kk)
          s += sc[((((0 * 2 + mt2) * 4 + kk) * 64 + ln) << 2) + rg];
        g4[gate] = s + p.att_b[gate * D + dj];
      }
      float c  = cAl[dj_l * 32 + mm];
      float cn = sigmoidf(g4[1]) * c + sigmoidf(g4[0]) * tanhfast(g4[2]);
      float hn = sigmoidf(g4[3]) * tanhfast(cn);
      cAl[dj_l * 32 + mm] = cn;
      size_t offP = (size_t)(kqiB * 8 + rB) * 1024 + (size_t)(mm >> 4) * 512
                  + (size_t)(lhB * 16 + (mm & 15)) * 8 + j0B + dj_l;
      stc_u16(p.hAb0 + offP, f2bf(hn));
    }
  }
  gbar(p.bars, ++ep);

  // ============ main loop ============
  for (int t = 0; t < TDEC; ++t) {
    const u16* hAcur  = (t & 1) ? p.hAb1 : p.hAb0;
    u16*       hAnxt  = (t & 1) ? p.hAb0 : p.hAb1;
    const u16* hGprev = (t & 1) ? p.hGb0 : p.hGb1;
    u16*       hGcur  = (t & 1) ? p.hGb1 : p.hGb0;
    const int  tp1 = (t + 1 < TDEC) ? (t + 1) : (TDEC - 1);
    const bool doatt = (t < TDEC - 1);

    // PG activation fragments (issued at end of PA, waited in PG)
    float4v e0,e1,e2,e3,e4,e5,e6,e7,e8,e9,e10,e11,e12,e13,e14,e15,e16,e17;

    // ---- PA: group-distributed attention (8 blocks per batch) + frames ----
    {
      // 1) hA[b] gather -> hq fp32 (padded 4x264 layout: bank-staggered slices)
      if (tid < 128) {
        const int kqi2 = tid >> 5, r2 = (tid >> 2) & 7, lh2 = tid & 3;
        float4v hv = ldc1(hAcur + (size_t)(kqi2 * 8 + r2) * 1024 + (size_t)(b >> 4) * 512
                          + (size_t)(lh2 * 16 + (b & 15)) * 8);
        short8 hs = __builtin_bit_cast(short8, hv);
        const int slice = tid >> 5;
        float* dst = hq + slice * 264 + ((tid * 8) & 255);
        #pragma unroll
        for (int j = 0; j < 8; ++j) dst[j] = bf2f((u16)hs[j]);
      }
      __syncthreads();
      // 2) query = hA @ Wq.T (redundant per block; conflict-free hq slices)
      {
        const int a = tid >> 2, qk = tid & 3;
        const u16* wrow = p.wqb + (size_t)a * 1024 + qk * 256;
        const float* hh = hq + qk * 264;
        float a0 = 0.f, a1 = 0.f;
        #pragma unroll 4
        for (int i = 0; i < 32; i += 2) {
          short8 wv8 = *(const short8*)(wrow + i * 8);
          #pragma unroll
          for (int j = 0; j < 8; ++j) a0 += bf2f((u16)wv8[j]) * hh[i * 8 + j];
          short8 wv9 = *(const short8*)(wrow + (i + 1) * 8);
          #pragma unroll
          for (int j = 0; j < 8; ++j) a1 += bf2f((u16)wv9[j]) * hh[(i + 1) * 8 + j];
        }
        qpart[tid] = a0 + a1;
      }
      __syncthreads();
      if (tid < 128)
        query[tid] = qpart[tid * 4] + qpart[tid * 4 + 1] + qpart[tid * 4 + 2]
                   + qpart[tid * 4 + 3] + qbias;
      // 3) location conv as MFMA, own tiles only; Abuf holds just 1-2 tiles
      float4v cacc0 = {0.f, 0.f, 0.f, 0.f};
      float4v cacc1 = {0.f, 0.f, 0.f, 0.f};
      #pragma unroll
      for (int pass = 0; pass < 2; ++pass) {
        __syncthreads();
        const float* src = pass ? scm : sp;
        {
          const int r = tid >> 5, kk = tid & 31;
          const int rowA = tile0 * 16 + r;
          Abuf[tid] = f2bf((rowA < 200 && kk < 31) ? src[rowA + kk] : 0.f);
          if (ntile == 2) {
            const int rowB = tile1 * 16 + r;
            Abuf[512 + tid] = f2bf((rowB < 200 && kk < 31) ? src[rowB + kk] : 0.f);
          }
        }
        __syncthreads();
        const short8 bfr = pass ? bfrag1 : bfrag0;
        {
          short8 av = *(const short8*)(Abuf + (size_t)cl_h * 32 + kq8c);
          cacc0 = __builtin_amdgcn_mfma_f32_16x16x32_bf16(av, bfr, cacc0, 0, 0, 0);
        }
        if (ntile == 2) {
          short8 av = *(const short8*)(Abuf + 512 + (size_t)cl_h * 32 + kq8c);
          cacc1 = __builtin_amdgcn_mfma_f32_16x16x32_bf16(av, bfr, cacc1, 0, 0, 0);
        }
      }
      // 4) energies for own tiles (pm/v_att hoisted -> pure VALU)
      {
        const float qv = query[wv * 16 + cl_h];
        #pragma unroll
        for (int i = 0; i < 4; ++i) {
          int tt = tile0 * 16 + ((lane >> 4) << 2) + i;
          float val = 0.f;
          if (tt < 200)
            val = tanhfast(qv + pmh[i] + cacc0[i]) * vvh;
          val += __shfl_down(val, 8, 16);
          val += __shfl_down(val, 4, 16);
          val += __shfl_down(val, 2, 16);
          val += __shfl_down(val, 1, 16);
          if (cl_h == 0 && tt < 200) epart[tt * 8 + wv] = val;
        }
        if (ntile == 2) {
          #pragma unroll
          for (int i = 0; i < 4; ++i) {
            int tt = tile1 * 16 + ((lane >> 4) << 2) + i;
            float val = 0.f;
            if (tt < 200)
              val = tanhfast(qv + pmh[4 + i] + cacc1[i]) * vvh;
            val += __shfl_down(val, 8, 16);
            val += __shfl_down(val, 4, 16);
            val += __shfl_down(val, 2, 16);
            val += __shfl_down(val, 1, 16);
            if (cl_h == 0 && tt < 200) epart[tt * 8 + wv] = val;
          }
        }
      }
      __syncthreads();
      // 5) energy write to MALL exchange buffer
      {
        const int ntt = ntile * 16;
        if (tid < ntt) {
          int tile = (tid < 16) ? tile0 : tile1;
          int tt = tile * 16 + (tid & 15);
          if (tt < 200) {
            float e = epart[tt * 8 + 0] + epart[tt * 8 + 1] + epart[tt * 8 + 2]
                    + epart[tt * 8 + 3] + epart[tt * 8 + 4] + epart[tt * 8 + 5]
                    + epart[tt * 8 + 6] + epart[tt * 8 + 7];
            stc_f32(p.eps + (size_t)b * 256 + tt, e);
          }
        }
        asm volatile("s_waitcnt vmcnt(0)" ::: "memory");
      }
      __syncthreads();
      if (tid == 0) atomicAdd(p.gc + (size_t)b * 32, 1u);
      // 6) frame(t-1) for batch b while the group converges
      if (t > 0) frame_do(t - 1);
      // 7) group sync: wait all 8 slices of batch b
      if (tid == 0) {
        while (__hip_atomic_load(p.gc + (size_t)b * 32, __ATOMIC_RELAXED,
                                 __HIP_MEMORY_SCOPE_AGENT) < 8u * (unsigned)(t + 1))
          __builtin_amdgcn_s_sleep(1);
      }
      __syncthreads();
      // 8) read full energies, mask
      if (tid < 200) {
        float e = ldc_f32(p.eps + (size_t)b * 256 + tid);
        e_w[tid] = (tid < lenb) ? e : -1.0e9f;
      }
      __syncthreads();
      // 9) softmax over 200 (redundant per block)
      float lm = (tid < 200) ? e_w[tid] : -3.0e38f;
      for (int o = 32; o > 0; o >>= 1) lm = fmaxf(lm, __shfl_down(lm, o, 64));
      if (lane == 0) red[wv] = lm;
      __syncthreads();
      float gm = red[0];
      #pragma unroll
      for (int i = 1; i < 8; ++i) gm = fmaxf(gm, red[i]);
      float ls = 0.f;
      float myp = 0.f;
      if (tid < 200) { myp = __expf(e_w[tid] - gm); ls = myp; }
      __syncthreads();
      if (tid < 200) e_w[tid] = myp;
      for (int o = 32; o > 0; o >>= 1) ls += __shfl_down(ls, o, 64);
      if (lane == 0) red[wv] = ls;
      __syncthreads();
      float inv = 0.f;
      #pragma unroll
      for (int i = 0; i < 8; ++i) inv += red[i];
      inv = 1.0f / inv;
      __syncthreads();
      if (tid < 200) {
        float wval = e_w[tid] * inv;
        e_w[tid] = wval;
        sp[15 + tid] = wval;
        scm[15 + tid] += wval;
        if (k == 0)
          p.out[ALIGN_OFF + ((size_t)b * TDEC + t) * TENC + tid] = wval;
      }
      __syncthreads();
      // 10) context slice: cols [64k, 64k+64), tt-slice [25*wv, 25*wv+25)
      {
        const int c = (k << 6) + lane;
        const float* ebase = p.enc + ((size_t)b * TENC + (size_t)(wv * 25)) * E + c;
        const float* ew = e_w + wv * 25;
        float a0 = 0.f, a1 = 0.f, a2 = 0.f, a3 = 0.f, a4 = 0.f;
        #pragma unroll
        for (int i = 0; i < 25; i += 5) {
          a0 += ew[i]     * ebase[(size_t)i * E];
          a1 += ew[i + 1] * ebase[(size_t)(i + 1) * E];
          a2 += ew[i + 2] * ebase[(size_t)(i + 2) * E];
          a3 += ew[i + 3] * ebase[(size_t)(i + 3) * E];
          a4 += ew[i + 4] * ebase[(size_t)(i + 4) * E];
        }
        cpart[(wv << 6) + lane] = ((a0 + a1) + (a2 + a3)) + a4;
      }
      __syncthreads();
      if (tid < 64) {
        float ssum = 0.f;
        #pragma unroll
        for (int s2 = 0; s2 < 8; ++s2) ssum += cpart[(s2 << 6) + tid];
        csum[tid] = ssum;
      }
      __syncthreads();
      if (tid < 16) {
        float4v v = { csum[tid * 4], csum[tid * 4 + 1], csum[tid * 4 + 2], csum[tid * 4 + 3] };
        stc_16B(p.ctxf + (size_t)(t & 1) * (E * B) + (size_t)b * 512
                + (size_t)(k << 6) + (size_t)tid * 4, v);
      }
      if (tid < 8) {
        const int q = 2 * k + (tid >> 2), lh = tid & 3;
        const int cb = tid * 8;
        unsigned w0 = (unsigned)f2bf(csum[cb])     | ((unsigned)f2bf(csum[cb + 1]) << 16);
        unsigned w1 = (unsigned)f2bf(csum[cb + 2]) | ((unsigned)f2bf(csum[cb + 3]) << 16);
        unsigned w2 = (unsigned)f2bf(csum[cb + 4]) | ((unsigned)f2bf(csum[cb + 5]) << 16);
        unsigned w3 = (unsigned)f2bf(csum[cb + 6]) | ((unsigned)f2bf(csum[cb + 7]) << 16);
        float4v pk;
        pk[0] = __builtin_bit_cast(float, w0);
        pk[1] = __builtin_bit_cast(float, w1);
        pk[2] = __builtin_bit_cast(float, w2);
        pk[3] = __builtin_bit_cast(float, w3);
        stc_16B(p.ctxb + (size_t)q * 1024 + (size_t)(b >> 4) * 512
                + (size_t)(lh * 16 + (b & 15)) * 8, pk);
      }
      // 11) issue PG fragment loads (stream overlaps barrier + PG head)
      ISSUE18();
    }
    gbar(p.bars, ++ep);

    // ---- PG: gen gates t + att gates t+1 (all 256 blocks) ----
    {
      const u16* _ct = p.ctxb + offCF;
      float4v c0, c1, c2, c3;
      LDC(c0, _ct); LDC(c1, _ct + 1024); LDC(c2, _ct + 2048); LDC(c3, _ct + 3072);
      // fragments first (ctx still in flight)
      asm volatile("s_waitcnt vmcnt(4)"
        : "+v"(e0),"+v"(e1),"+v"(e2),"+v"(e3),"+v"(e4),"+v"(e5),"+v"(e6),"+v"(e7),
          "+v"(e8),"+v"(e9),"+v"(e10),"+v"(e11),"+v"(e12),"+v"(e13),"+v"(e14),"+v"(e15),
          "+v"(e16),"+v"(e17)
        :: "memory");
      float4v accA = {0.f, 0.f, 0.f, 0.f};
      float4v accG = {0.f, 0.f, 0.f, 0.f};
      MFA(0, e0);  MFA(1, e1);
      MFA(2, e2);  MFG(0, e2);
      MFA(3, e3);  MFG(1, e3);
      MFA(4, e4);  MFG(2, e4);
      MFA(5, e5);  MFG(3, e5);
      MFA(6, e6);  MFG(4, e6);
      MFA(7, e7);  MFG(5, e7);
      MFA(8, e8);  MFG(6, e8);
      MFA(9, e9);  MFG(7, e9);
      MFG(8, e10); MFG(9, e11); MFG(10, e12); MFG(11, e13);
      MFG(12, e14); MFG(13, e15); MFG(14, e16); MFG(15, e17);
      __builtin_amdgcn_sched_barrier(0);
      asm volatile("s_waitcnt vmcnt(0)"
        : "+v"(c0),"+v"(c1),"+v"(c2),"+v"(c3) :: "memory");
      MFA(10, c0); MFG(16, c0);
      MFA(11, c1); MFG(17, c1);
      MFA(12, c2); MFG(18, c2);
      MFA(13, c3); MFG(19, c3);
      float* rA = sc + ((((0 * 2 + mt) * 4 + kqi) * 64 + lane) << 2);
      rA[0] = accA[0]; rA[1] = accA[1]; rA[2] = accA[2]; rA[3] = accA[3];
      float* rG = sc + ((((1 * 2 + mt) * 4 + kqi) * 64 + lane) << 2);
      rG[0] = accG[0]; rG[1] = accG[1]; rG[2] = accG[2]; rG[3] = accG[3];
      __syncthreads();
      if (tid < 256) {
        const int gg = tid >> 7, dj_l = (tid >> 5) & 3, mm = tid & 31;
        if (gg == 1 || doatt) {
          const int dj = blk * 4 + dj_l;
          const int mt2 = mm >> 4, m2 = mm & 15;
          float g4[4];
          #pragma unroll
          for (int gate = 0; gate < 4; ++gate) {
            int ln = ((m2 >> 2) << 4) | (dj_l * 4 + gate);
            int rg = m2 & 3;
            float s = 0.f;
            #pragma unroll
            for (int kk = 0; kk < 4; ++kk)
              s += sc[((((gg * 2 + mt2) * 4 + kk) * 64 + ln) << 2) + rg];
            g4[gate] = s + biash[gate];
          }
          float* cl2 = (gg == 0) ? cAl : cGl;
          float c  = cl2[dj_l * 32 + mm];
          float cn = sigmoidf(g4[1]) * c + sigmoidf(g4[0]) * tanhfast(g4[2]);
          float hn = sigmoidf(g4[3]) * tanhfast(cn);
          cl2[dj_l * 32 + mm] = cn;
          hstg[tid] = hn;
        }
      }
      __syncthreads();
      // packed fragment-major stores: 64 threads, 8B/16B transactions
      if (tid < 64) {
        const int gg = tid >> 5, mm = tid & 31;
        const size_t offP = (size_t)(kqiB * 8 + rB) * 1024 + (size_t)(mm >> 4) * 512
                          + (size_t)(lhB * 16 + (mm & 15)) * 8 + j0B;
        if (gg == 0) {
          if (doatt) {
            unsigned w0 = (unsigned)f2bf(hstg[mm])      | ((unsigned)f2bf(hstg[32 + mm]) << 16);
            unsigned w1 = (unsigned)f2bf(hstg[64 + mm]) | ((unsigned)f2bf(hstg[96 + mm]) << 16);
            uint2v pk = {w0, w1};
            stc_8B(hAnxt + offP, pk);
          }
        } else {
          float f0 = hstg[128 + mm], f1 = hstg[160 + mm];
          float f2 = hstg[192 + mm], f3 = hstg[224 + mm];
          unsigned w0 = (unsigned)f2bf(f0) | ((unsigned)f2bf(f1) << 16);
          unsigned w1 = (unsigned)f2bf(f2) | ((unsigned)f2bf(f3) << 16);
          uint2v pk = {w0, w1};
          stc_8B(hGcur + offP, pk);
          float4v pf = {f0, f1, f2, f3};
          stc_16B(p.hGf + (size_t)mm * 1024 + blk * 4, pf);
        }
      }
    }
    gbar(p.bars, ++ep);
  }

  // ---- final frame (ft = 599), group-distributed ----
  frame_do(TDEC - 1);
}

// ---------------------------------------------------------------------------
// Prenet -> preB fragment-major per t
__global__ __launch_bounds__(256) void prenet_kernel(
    const float* __restrict__ target, const float* __restrict__ W1, const float* __restrict__ b1,
    const float* __restrict__ W2, const float* __restrict__ b2, u16* __restrict__ preB)
{
  const int t = blockIdx.x;
  const int tid = threadIdx.x;
  __shared__ float tg[B][M];
  __shared__ float x1[B][P];
  for (int i = tid; i < B * M; i += 256) {
    int b = i / M, m = i - b * M;
    tg[b][m] = (t == 0) ? 0.0f : target[(size_t)b * M * TDEC + (size_t)m * TDEC + (t - 1)];
  }
  __syncthreads();
  for (int i = tid; i < B * P; i += 256) {
    int b = i >> 8, j = i & 255;
    const float* w = W1 + (size_t)j * M;
    float acc = b1[j];
    for (int m = 0; m < M; ++m) acc += w[m] * tg[b][m];
    x1[b][j] = fmaxf(acc, 0.0f);
  }
  __syncthreads();
  for (int i = tid; i < B * P; i += 256) {
    int b = i >> 8, j = i & 255;
    const float* w = W2 + (size_t)j * P;
    float acc = b2[j];
    for (int m = 0; m < P; m += 4)
      acc += w[m]*x1[b][m] + w[m+1]*x1[b][m+1] + w[m+2]*x1[b][m+2] + w[m+3]*x1[b][m+3];
    int kqi = j >> 6, r = (j >> 5) & 1, lh = (j >> 3) & 3, jj = j & 7;
    size_t off = (size_t)(kqi * 2 + r) * 1024 + (size_t)(b >> 4) * 512
               + (size_t)(lh * 16 + (b & 15)) * 8 + jj;
    preB[(size_t)t * (B * P) + off] = f2bf(fmaxf(acc, 0.0f));
  }
}

// ---------------------------------------------------------------------------
__global__ __launch_bounds__(256) void procmem_kernel(
    const float* __restrict__ enc, const float* __restrict__ Wm, float* __restrict__ pm)
{
  const int blk = blockIdx.x;
  const int b = blk >> 3;
  const int t0 = (blk & 7) * 25;
  for (int i = threadIdx.x; i < 25 * A; i += 256) {
    int tl = i >> 7, a = i & 127;
    int t = t0 + tl;
    const float* x = enc + ((size_t)b * TENC + t) * E;
    const float* w = Wm + (size_t)a * E;
    float acc = 0.0f;
    for (int k = 0; k < E; k += 4)
      acc += w[k]*x[k] + w[k+1]*x[k+1] + w[k+2]*x[k+2] + w[k+3]*x[k+3];
    pm[((size_t)b * TENC + t) * A + a] = acc;
  }
}

// ---------------------------------------------------------------------------
__global__ __launch_bounds__(256) void kpk_kernel(
    const float* __restrict__ lker, const float* __restrict__ Wloc, u16* __restrict__ kpk)
{
  int idx = blockIdx.x * 256 + threadIdx.x;
  if (idx >= 8192) return;
  int j = idx & 7, ln = (idx >> 3) & 63, tn = (idx >> 9) & 7, pass = idx >> 12;
  int a = tn * 16 + (ln & 15);
  int k = ((ln >> 4) << 3) + j;
  float v = 0.f;
  if (k < KC) {
    for (int f = 0; f < LF; ++f)
      v += Wloc[a * LF + f] * lker[f * (2 * KC) + pass * KC + k];
  }
  kpk[idx] = f2bf(v);
}

// ---------------------------------------------------------------------------
__global__ __launch_bounds__(256) void wqpack_kernel(
    const float* __restrict__ Wq, u16* __restrict__ wqb)
{
  int idx = blockIdx.x * 256 + threadIdx.x;
  if (idx < A * D) wqb[idx] = f2bf(Wq[idx]);
}

// ---------------------------------------------------------------------------
// fwb[j][k]: j=0..79 frame rows, j=80 stop row; bf16
__global__ __launch_bounds__(256) void fwpack_kernel(
    const float* __restrict__ frame_W, const float* __restrict__ stop_W, u16* __restrict__ fwb)
{
  int idx = blockIdx.x * 256 + threadIdx.x;
  if (idx >= 81 * 1536) return;
  int j = idx / 1536, k = idx - j * 1536;
  float v = (j < M) ? frame_W[(size_t)j * 1536 + k] : stop_W[k];
  fwb[idx] = f2bf(v);
}

// ---------------------------------------------------------------------------
extern "C" void kernel_launch(void* const* d_in, const int* in_sizes, int n_in,
                              void* d_out, int out_size, void* d_ws, size_t ws_size,
                              hipStream_t stream)
{
  const float* enc      = (const float*)d_in[0];
  const int*   lens     = (const int*)  d_in[1];
  const float* target   = (const float*)d_in[2];
  const float* pW1      = (const float*)d_in[4];
  const float* pb1      = (const float*)d_in[5];
  const float* pW2      = (const float*)d_in[6];
  const float* pb2      = (const float*)d_in[7];
  const float* att_Wih  = (const float*)d_in[8];
  const float* att_Whh  = (const float*)d_in[9];
  const float* att_b    = (const float*)d_in[10];
  const float* gen_Wih  = (const float*)d_in[11];
  const float* gen_Whh  = (const float*)d_in[12];
  const float* gen_b    = (const float*)d_in[13];
  const float* Wq       = (const float*)d_in[14];
  const float* Wm       = (const float*)d_in[15];
  const float* lker     = (const float*)d_in[16];
  const float* Wloc     = (const float*)d_in[17];
  const float* v_att    = (const float*)d_in[18];
  const float* b_att    = (const float*)d_in[19];
  const float* frame_W  = (const float*)d_in[20];
  const float* frame_b  = (const float*)d_in[21];
  const float* stop_W   = (const float*)d_in[22];
  const float* stop_b   = (const float*)d_in[23];

  float* ws = (float*)d_ws;
  float* st = ws + OFF_ST;

  Params p;
  p.enc = enc; p.lens = lens;
  p.att_Wih = att_Wih; p.att_Whh = att_Whh; p.att_b = att_b;
  p.gen_Wih = gen_Wih; p.gen_Whh = gen_Whh; p.gen_b = gen_b;
  p.v_att = v_att; p.b_att = b_att;
  p.frame_b = frame_b; p.stop_b = stop_b;
  p.pm   = ws + OFF_PM;
  p.preB = (const u16*)(ws + OFF_PREB);
  p.kpk  = (const u16*)(ws + OFF_KPK);
  p.wqb  = (const u16*)(ws + OFF_WQB);
  p.fwb  = (const u16*)(ws + OFF_FWB);
  p.hAb0 = (u16*)(st + ST_HAB0);
  p.hAb1 = (u16*)(st + ST_HAB1);
  p.hGb0 = (u16*)(st + ST_HGB0);
  p.hGb1 = (u16*)(st + ST_HGB1);
  p.ctxb = (u16*)(st + ST_CTXB);
  p.ctxf = st + ST_CTXF;
  p.hGf  = st + ST_HGF;
  p.bars = (unsigned*)(st + ST_BARS);
  p.eps  = st + ST_EPS;
  p.gc   = (unsigned*)(st + ST_GC);
  p.out  = (float*)d_out;

  hipMemsetAsync((void*)st, 0, N_STATE * sizeof(float), stream);

  kpk_kernel    <<<32, 256, 0, stream>>>(lker, Wloc, (u16*)(ws + OFF_KPK));
  wqpack_kernel <<<512, 256, 0, stream>>>(Wq, (u16*)(ws + OFF_WQB));
  fwpack_kernel <<<486, 256, 0, stream>>>(frame_W, stop_W, (u16*)(ws + OFF_FWB));
  prenet_kernel <<<TDEC, 256, 0, stream>>>(target, pW1, pb1, pW2, pb2, (u16*)(ws + OFF_PREB));
  procmem_kernel<<<256, 256, 0, stream>>>(enc, Wm, ws + OFF_PM);

  hipFuncSetAttribute((const void*)persist_kernel,
                      hipFuncAttributeMaxDynamicSharedMemorySize, SMEM_BYTES);
  persist_kernel<<<256, 512, SMEM_BYTES, stream>>>(p);
}

// Round 11
// 18103.697 us; speedup vs baseline: 1.1695x; 1.1695x over previous
//
#include <hip/hip_runtime.h>
#include <hip/hip_bf16.h>
#include <cstddef>

#define B     32
#define TENC  200
#define E     512
#define D     1024
#define P     256
#define M     80
#define TDEC  600
#define A     128
#define KC    31
#define LF    32

typedef __attribute__((ext_vector_type(8))) short short8;
typedef __attribute__((ext_vector_type(4))) float float4v;
typedef __attribute__((ext_vector_type(2))) unsigned int uint2v;
typedef unsigned short u16;

// output offsets (floats)
#define SPEC_OFF  0
#define STOP_OFF  ((size_t)B * TDEC * M)
#define ALIGN_OFF (STOP_OFF + (size_t)B * TDEC)

// ---------------- workspace layout (float units) ----------------
constexpr size_t OFF_PM   = 0;                    // fp32 [b][t][a]   819200
constexpr size_t OFF_PREB = 819200;               // bf16 fragment-major [t][8192] 2457600 f
constexpr size_t OFF_KPK  = 3276800;              // bf16 packed keff 8192 -> 4096 f
constexpr size_t OFF_WQB  = 3280896;              // bf16 Wq 131072 -> 65536 f
constexpr size_t OFF_FWB  = 3346432;              // bf16 frame/stop W 81*1536 -> 62208 f
constexpr size_t OFF_ST   = 3408640;
// state region (zeroed each call), float offsets relative to OFF_ST:
constexpr size_t ST_HAB0 = 0;       // bf16 fragment-major 32768 u16 -> 16384 f
constexpr size_t ST_HAB1 = 16384;
constexpr size_t ST_HGB0 = 32768;
constexpr size_t ST_HGB1 = 49152;
constexpr size_t ST_CTXB = 65536;   // bf16 fragment-major 16384 u16 -> 8192 f
constexpr size_t ST_CTXF = 73728;   // fp32 2 x [b][512] -> 32768 f
constexpr size_t ST_HGF  = 106496;  // fp32 [b][1024] -> 32768 f
constexpr size_t ST_BARS = 139264;  // 1344 f barrier counters + release lines
constexpr size_t ST_EPS  = 140608;  // fp32 32 x 256 energy exchange = 8192 f
constexpr size_t ST_GC   = 148800;  // 32 group counters x 32 f = 1024 f
constexpr size_t N_STATE = 149824;

// ---------------- LDS layout (bytes) ----------------
constexpr int LDS_ATTW = 0;          // 56*512*2  = 57344
constexpr int LDS_GENW = 57344;      // 80*512*2  = 81920
constexpr int LDS_SC   = 139264;     // 5184 floats scratch (20736 B)
constexpr int LDS_SP   = 160000;     // 232 f padded wprev
constexpr int LDS_SCM  = 160928;     // 232 f padded wcum
constexpr int LDS_CA   = 161856;     // 128 f
constexpr int LDS_CG   = 162368;     // 128 f
constexpr int SMEM_BYTES = 162880;   // <= 163840

struct Params {
  const float* enc; const int* lens;
  const float *att_Wih, *att_Whh, *att_b, *gen_Wih, *gen_Whh, *gen_b;
  const float *v_att, *b_att, *frame_b, *stop_b;
  const float *pm;
  const u16 *preB, *kpk, *wqb, *fwb;
  u16 *hAb0, *hAb1, *hGb0, *hGb1, *ctxb;
  float *ctxf, *hGf;
  unsigned* bars;
  float* eps;
  unsigned* gc;
  float* out;
};

__device__ __forceinline__ float sigmoidf(float x) { return 1.0f / (1.0f + __expf(-x)); }
__device__ __forceinline__ float tanhfast(float x) {
  float ax = fabsf(x);
  float e = __expf(2.0f * ax);
  float t = 1.0f - 2.0f / (e + 1.0f);
  return copysignf(t, x);
}
__device__ __forceinline__ u16 f2bf(float x) {
  __hip_bfloat16 h = __float2bfloat16(x);
  return __builtin_bit_cast(u16, h);
}
__device__ __forceinline__ float bf2f(u16 u) {
  unsigned v = ((unsigned)u) << 16;
  return __builtin_bit_cast(float, v);
}

// ---- MALL-coherent access helpers (bypass non-coherent per-XCD L2) ----
#define LDC(r, p) asm volatile("global_load_dwordx4 %0, %1, off sc0 sc1" : "=v"(r) : "v"(p))
// plain cached load (immutable data during the persistent kernel):
#define LDP(r, p) asm volatile("global_load_dwordx4 %0, %1, off" : "=v"(r) : "v"(p))

__device__ __forceinline__ float4v ldc1(const void* p) {
  float4v r;
  LDC(r, p);
  asm volatile("s_waitcnt vmcnt(0)" : "+v"(r) :: "memory");
  return r;
}
__device__ __forceinline__ float ldc_f32(const float* pf) {
  float r;
  asm volatile("global_load_dword %0, %1, off sc0 sc1" : "=v"(r) : "v"(pf));
  asm volatile("s_waitcnt vmcnt(0)" : "+v"(r) :: "memory");
  return r;
}
__device__ __forceinline__ void stc_f32(float* p, float v) {
  asm volatile("global_store_dword %0, %1, off sc0 sc1" :: "v"(p), "v"(v) : "memory");
}
__device__ __forceinline__ void stc_u16(u16* p, u16 v) {
  unsigned vv = v;
  asm volatile("global_store_short %0, %1, off sc0 sc1" :: "v"(p), "v"(vv) : "memory");
}
__device__ __forceinline__ void stc_8B(void* p, uint2v v) {
  asm volatile("global_store_dwordx2 %0, %1, off sc0 sc1" :: "v"(p), "v"(v) : "memory");
}
__device__ __forceinline__ void stc_16B(void* p, float4v v) {
  asm volatile("global_store_dwordx4 %0, %1, off sc0 sc1" :: "v"(p), "v"(v) : "memory");
}

// ---------------------------------------------------------------------------
// grid barrier WITHOUT agent-scope fences.  Arrival: 16 group counters +
// central.  Release: 16 per-group lines (16 pollers/line).
__device__ __forceinline__ void gbar(unsigned* bars, int ep) {
  __syncthreads();
  if (threadIdx.x == 0) {
    const int grp = blockIdx.x >> 4;          // 16 groups x 16 blocks
    unsigned old = atomicAdd(bars + (grp << 5), 1u);
    if (old + 1u == (unsigned)ep * 16u) {
      unsigned cold = atomicAdd(bars + 768, 1u);
      if (cold + 1u == (unsigned)ep * 16u) {
        #pragma unroll
        for (int g2 = 0; g2 < 16; ++g2)
          __hip_atomic_store(bars + 800 + (g2 << 5), (unsigned)ep,
                             __ATOMIC_RELAXED, __HIP_MEMORY_SCOPE_AGENT);
      }
    }
    while (__hip_atomic_load(bars + 800 + (grp << 5), __ATOMIC_RELAXED,
                             __HIP_MEMORY_SCOPE_AGENT) < (unsigned)ep)
      __builtin_amdgcn_s_sleep(2);
  }
  __syncthreads();
}

// ---------------------------------------------------------------------------
// Group-distributed frame/stop projection for step ft, batch b, slice k.
// Block k computes rows [k*10, k*10+10) (+ stop row 80 for k==0).
// Per-step weight loads (cached, L2-warm) — NO register hoisting (r9/r10
// showed hoisting spills at the compiler's fixed 128-VGPR budget).
__device__ __forceinline__ void frame_group(const Params& p, int ft, int b, int k,
                                            int wv, int lane, int tid, float* X)
{
  const int slot = ft & 1;
  if (tid < 384) {
    const float* src = (tid < 256)
        ? (p.hGf + (size_t)b * 1024 + (size_t)tid * 4)
        : (p.ctxf + (size_t)slot * (E * B) + (size_t)b * 512 + (size_t)(tid - 256) * 4);
    float4v v = ldc1(src);
    *(float4v*)(X + tid * 4) = v;
  }
  __syncthreads();
  const int nrows = (k == 0) ? 11 : 10;
  for (int jj = wv; jj < nrows; jj += 8) {
    int row = (jj < 10) ? (k * 10 + jj) : 80;
    const u16* w = p.fwb + (size_t)row * 1536 + lane;
    float acc = 0.f, acc2 = 0.f;
    #pragma unroll
    for (int i = 0; i < 24; i += 2) {
      acc  += bf2f(w[(size_t)i * 64])       * X[lane + i * 64];
      acc2 += bf2f(w[(size_t)(i + 1) * 64]) * X[lane + (i + 1) * 64];
    }
    acc += acc2;
    for (int o = 32; o > 0; o >>= 1) acc += __shfl_down(acc, o, 64);
    if (lane == 0) {
      if (row < M) p.out[SPEC_OFF + (size_t)b * TDEC * M + (size_t)ft * M + row] = acc + p.frame_b[row];
      else         p.out[STOP_OFF + (size_t)b * TDEC + ft] = acc + p.stop_b[0];
    }
  }
  __syncthreads();
}

// ---------------------------------------------------------------------------
// Fragment-major layouts (u16 offsets), global k-chunk index kappa:
//   off = kappa*1024 + (m>>4)*512 + lane*8   (consumer wave reads 1KB bursts)

__global__ void __launch_bounds__(512, 2) persist_kernel(Params p) {
  extern __shared__ char smem[];
  __hip_bfloat16* attw = (__hip_bfloat16*)(smem + LDS_ATTW);
  __hip_bfloat16* genw = (__hip_bfloat16*)(smem + LDS_GENW);
  float* sc   = (float*)(smem + LDS_SC);
  float* sp   = (float*)(smem + LDS_SP);
  float* scm  = (float*)(smem + LDS_SCM);
  float* cAl  = (float*)(smem + LDS_CA);
  float* cGl  = (float*)(smem + LDS_CG);
  // PA-phase scratch sublayout (time-multiplexed):
  float* hq    = sc;                       // [0..1056) padded 4 x 264 gather
  float* qpart = sc + 1088;                // [1088..1600)
  u16*   Abuf  = (u16*)(smem + LDS_SC + 6784);   // floats [1696..2208), conv only
  float* cpart = sc + 2048;                // ctx partials [2048..2560) (conv-dead)
  float* csum  = sc + 2560;                // ctx sums [2560..2624)
  float* query = sc + 2624;                // [2624..2752)
  float* red   = sc + 2752;                // [2752..2760)
  float* epart = sc + 3360;                // [3360..4960)
  float* e_w   = sc + 4960;                // [4960..5160)
  float* Xf    = sc;                       // frame proto [0..1536) (gather/query dead)
  float* hstg  = sc + 4200;                // PG epilogue hn stage (PG-phase only)

  const int tid  = threadIdx.x;
  const int blk  = blockIdx.x;
  const int lane = tid & 63;
  const int wv   = tid >> 6;
  const int b    = blk >> 3;   // group = batch
  const int k    = blk & 7;    // slice within group
  int ep = 0;

  // ============ prolog: pack weight slices into LDS (unchanged scheme) ============
  for (int idx = tid; idx < 56 * 512; idx += 512) {
    int k0 = idx >> 9, e = idx & 511, ln = e >> 3, j = e & 7, r = ln & 15;
    int row = (r & 3) * D + blk * 4 + (r >> 2);
    int kq8 = ((ln >> 4) << 3) + j;
    int w = k0 / 14, s = k0 - w * 14;
    float v;
    if (s < 2) {
      int kk = (w * 2 + s) * 32 + kq8;
      v = p.att_Wih[(size_t)row * 768 + kk];
    } else if (s < 10) {
      int kk = (w * 8 + (s - 2)) * 32 + kq8;
      v = p.att_Whh[(size_t)row * D + kk];
    } else {
      int kk = 256 + (w * 4 + (s - 10)) * 32 + kq8;
      v = p.att_Wih[(size_t)row * 768 + kk];
    }
    attw[idx] = __float2bfloat16(v);
  }
  for (int idx = tid; idx < 80 * 512; idx += 512) {
    int k0 = idx >> 9, e = idx & 511, ln = e >> 3, j = e & 7, r = ln & 15;
    int row = (r & 3) * D + blk * 4 + (r >> 2);
    int kq8 = ((ln >> 4) << 3) + j;
    int w = k0 / 20, s = k0 - w * 20;
    float v;
    if (s < 8) {
      int kk = (w * 8 + s) * 32 + kq8;
      v = p.gen_Wih[(size_t)row * 1536 + kk];
    } else if (s < 16) {
      int kk = (w * 8 + (s - 8)) * 32 + kq8;
      v = p.gen_Whh[(size_t)row * D + kk];
    } else {
      int kk = 1024 + (w * 4 + (s - 16)) * 32 + kq8;
      v = p.gen_Wih[(size_t)row * 1536 + kk];
    }
    genw[idx] = __float2bfloat16(v);
  }
  if (tid < 128) { cAl[tid] = 0.f; cGl[tid] = 0.f; }
  for (int i = tid; i < 232; i += 512) { sp[i] = 0.f; scm[i] = 0.f; }
  __syncthreads();

  // per-thread constant geometry
  const int mt  = wv & 1, kqi = wv >> 1;
  const size_t offPreF = (size_t)kqi * 2048 + (size_t)mt * 512 + (size_t)lane * 8;
  const size_t offHF   = (size_t)kqi * 8192 + (size_t)mt * 512 + (size_t)lane * 8;
  const size_t offCF   = (size_t)kqi * 4096 + (size_t)mt * 512 + (size_t)lane * 8;
  const __hip_bfloat16* awp = attw + (size_t)(kqi * 14) * 512 + (size_t)lane * 8;
  const __hip_bfloat16* gwp = genw + (size_t)(kqi * 20) * 512 + (size_t)lane * 8;
  const int kqiB = blk >> 6, rB = (blk >> 3) & 7, lhB = (blk >> 1) & 3, j0B = (blk & 1) * 4;

#define MFA(i, reg) accA = __builtin_amdgcn_mfma_f32_16x16x32_bf16( \
    __builtin_bit_cast(short8, reg), *(const short8*)(awp + (size_t)(i) * 512), accA, 0, 0, 0)
#define MFG(i, reg) accG = __builtin_amdgcn_mfma_f32_16x16x32_bf16( \
    __builtin_bit_cast(short8, reg), *(const short8*)(gwp + (size_t)(i) * 512), accG, 0, 0, 0)

#define ISSUE18() do { \
    const u16* _pr = p.preB + (size_t)tp1 * (B * P) + offPreF; \
    const u16* _ha = hAcur + offHF; \
    const u16* _hg = hGprev + offHF; \
    LDP(e0, _pr); LDP(e1, _pr + 1024); \
    LDC(e2, _ha); LDC(e3, _ha + 1024); LDC(e4, _ha + 2048); LDC(e5, _ha + 3072); \
    LDC(e6, _ha + 4096); LDC(e7, _ha + 5120); LDC(e8, _ha + 6144); LDC(e9, _ha + 7168); \
    LDC(e10, _hg); LDC(e11, _hg + 1024); LDC(e12, _hg + 2048); LDC(e13, _hg + 3072); \
    LDC(e14, _hg + 4096); LDC(e15, _hg + 5120); LDC(e16, _hg + 6144); LDC(e17, _hg + 7168); \
  } while (0)

  // ============ pre-phase: att gates for t=0 (ctx=0, hA=0 => only preB term) ============
  {
    const u16* _pr = p.preB + offPreF;
    float4v e0, e1;
    LDP(e0, _pr); LDP(e1, _pr + 1024);
    asm volatile("s_waitcnt vmcnt(0)" : "+v"(e0), "+v"(e1) :: "memory");
    float4v accA = {0.f, 0.f, 0.f, 0.f};
    MFA(0, e0); MFA(1, e1);
    float* r = sc + ((((0 * 2 + mt) * 4 + kqi) * 64 + lane) << 2);
    r[0] = accA[0]; r[1] = accA[1]; r[2] = accA[2]; r[3] = accA[3];
    __syncthreads();
    if (tid < 128) {
      int dj_l = (tid >> 5) & 3, mm = tid & 31;
      int dj = blk * 4 + dj_l;
      int mt2 = mm >> 4, m2 = mm & 15;
      float g4[4];
      #pragma unroll
      for (int gate = 0; gate < 4; ++gate) {
        int ln = ((m2 >> 2) << 4) | (dj_l * 4 + gate);
        int rg = m2 & 3;
        float s = 0.f;
        #pragma unroll
        for (int kk = 0; kk < 4; ++kk)
          s += sc[((((0 * 2 + mt2) * 4 + kk) * 64 + ln) << 2) + rg];
        g4[gate] = s + p.att_b[gate * D + dj];
      }
      float c  = cAl[dj_l * 32 + mm];
      float cn = sigmoidf(g4[1]) * c + sigmoidf(g4[0]) * tanhfast(g4[2]);
      float hn = sigmoidf(g4[3]) * tanhfast(cn);
      cAl[dj_l * 32 + mm] = cn;
      size_t offP = (size_t)(kqiB * 8 + rB) * 1024 + (size_t)(mm >> 4) * 512
                  + (size_t)(lhB * 16 + (mm & 15)) * 8 + j0B + dj_l;
      stc_u16(p.hAb0 + offP, f2bf(hn));
    }
  }
  gbar(p.bars, ++ep);

  // ============ main loop ============
  for (int t = 0; t < TDEC; ++t) {
    const u16* hAcur  = (t & 1) ? p.hAb1 : p.hAb0;
    u16*       hAnxt  = (t & 1) ? p.hAb0 : p.hAb1;
    const u16* hGprev = (t & 1) ? p.hGb0 : p.hGb1;
    u16*       hGcur  = (t & 1) ? p.hGb1 : p.hGb0;
    const int  tp1 = (t + 1 < TDEC) ? (t + 1) : (TDEC - 1);
    const bool doatt = (t < TDEC - 1);

    // PG activation fragments (issued at end of PA, waited in PG)
    float4v e0,e1,e2,e3,e4,e5,e6,e7,e8,e9,e10,e11,e12,e13,e14,e15,e16,e17;

    // ---- PA: group-distributed attention (8 blocks per batch) + frames ----
    {
      // 1) hA[b] gather -> hq fp32 (padded 4x264 layout: bank-staggered slices)
      if (tid < 128) {
        const int kqi2 = tid >> 5, r2 = (tid >> 2) & 7, lh2 = tid & 3;
        float4v hv = ldc1(hAcur + (size_t)(kqi2 * 8 + r2) * 1024 + (size_t)(b >> 4) * 512
                          + (size_t)(lh2 * 16 + (b & 15)) * 8);
        short8 hs = __builtin_bit_cast(short8, hv);
        const int slice = tid >> 5;
        float* dst = hq + slice * 264 + ((tid * 8) & 255);
        #pragma unroll
        for (int j = 0; j < 8; ++j) dst[j] = bf2f((u16)hs[j]);
      }
      __syncthreads();
      // 2) query = hA @ Wq.T (redundant per block; conflict-free hq slices)
      {
        const int a = tid >> 2, qk = tid & 3;
        const u16* wrow = p.wqb + (size_t)a * 1024 + qk * 256;
        const float* hh = hq + qk * 264;
        float a0 = 0.f, a1 = 0.f;
        #pragma unroll 4
        for (int i = 0; i < 32; i += 2) {
          short8 wv8 = *(const short8*)(wrow + i * 8);
          #pragma unroll
          for (int j = 0; j < 8; ++j) a0 += bf2f((u16)wv8[j]) * hh[i * 8 + j];
          short8 wv9 = *(const short8*)(wrow + (i + 1) * 8);
          #pragma unroll
          for (int j = 0; j < 8; ++j) a1 += bf2f((u16)wv9[j]) * hh[(i + 1) * 8 + j];
        }
        qpart[tid] = a0 + a1;
      }
      __syncthreads();
      if (tid < 128)
        query[tid] = qpart[tid * 4] + qpart[tid * 4 + 1] + qpart[tid * 4 + 2]
                   + qpart[tid * 4 + 3] + p.b_att[tid];
      // 3) location conv as MFMA, own tiles only; Abuf holds just 1-2 tiles
      const int tile0 = k, tile1 = k + 8;
      const int ntile = (k <= 4) ? 2 : 1;
      float4v cacc0 = {0.f, 0.f, 0.f, 0.f};
      float4v cacc1 = {0.f, 0.f, 0.f, 0.f};
      const int tn = wv, cl = lane & 15, kq8 = (lane >> 4) << 3;
      #pragma unroll
      for (int pass = 0; pass < 2; ++pass) {
        __syncthreads();
        const float* src = pass ? scm : sp;
        {
          const int r = tid >> 5, kk = tid & 31;
          const int rowA = tile0 * 16 + r;
          Abuf[tid] = f2bf((rowA < 200 && kk < 31) ? src[rowA + kk] : 0.f);
          if (ntile == 2) {
            const int rowB = tile1 * 16 + r;
            Abuf[512 + tid] = f2bf((rowB < 200 && kk < 31) ? src[rowB + kk] : 0.f);
          }
        }
        __syncthreads();
        short8 bfrag = *(const short8*)(p.kpk + ((size_t)(pass * 8 + tn) * 64 + lane) * 8);
        {
          short8 av = *(const short8*)(Abuf + (size_t)cl * 32 + kq8);
          cacc0 = __builtin_amdgcn_mfma_f32_16x16x32_bf16(av, bfrag, cacc0, 0, 0, 0);
        }
        if (ntile == 2) {
          short8 av = *(const short8*)(Abuf + 512 + (size_t)cl * 32 + kq8);
          cacc1 = __builtin_amdgcn_mfma_f32_16x16x32_bf16(av, bfrag, cacc1, 0, 0, 0);
        }
      }
      // 4) energies for own tiles (per-step pm/v_att loads, L2-warm as in r8)
      {
        const int a = tn * 16 + cl;
        const float qv = query[a];
        const float vv = p.v_att[a];
        #pragma unroll
        for (int i = 0; i < 4; ++i) {
          int tt = tile0 * 16 + ((lane >> 4) << 2) + i;
          float val = 0.f;
          if (tt < 200)
            val = tanhfast(qv + p.pm[((size_t)b * TENC + tt) * A + a] + cacc0[i]) * vv;
          val += __shfl_down(val, 8, 16);
          val += __shfl_down(val, 4, 16);
          val += __shfl_down(val, 2, 16);
          val += __shfl_down(val, 1, 16);
          if (cl == 0 && tt < 200) epart[tt * 8 + tn] = val;
        }
        if (ntile == 2) {
          #pragma unroll
          for (int i = 0; i < 4; ++i) {
            int tt = tile1 * 16 + ((lane >> 4) << 2) + i;
            float val = 0.f;
            if (tt < 200)
              val = tanhfast(qv + p.pm[((size_t)b * TENC + tt) * A + a] + cacc1[i]) * vv;
            val += __shfl_down(val, 8, 16);
            val += __shfl_down(val, 4, 16);
            val += __shfl_down(val, 2, 16);
            val += __shfl_down(val, 1, 16);
            if (cl == 0 && tt < 200) epart[tt * 8 + tn] = val;
          }
        }
      }
      __syncthreads();
      // 5) energy write to MALL exchange buffer
      {
        const int ntt = ntile * 16;
        if (tid < ntt) {
          int tile = (tid < 16) ? tile0 : tile1;
          int tt = tile * 16 + (tid & 15);
          if (tt < 200) {
            float e = epart[tt * 8 + 0] + epart[tt * 8 + 1] + epart[tt * 8 + 2]
                    + epart[tt * 8 + 3] + epart[tt * 8 + 4] + epart[tt * 8 + 5]
                    + epart[tt * 8 + 6] + epart[tt * 8 + 7];
            stc_f32(p.eps + (size_t)b * 256 + tt, e);
          }
        }
        asm volatile("s_waitcnt vmcnt(0)" ::: "memory");
      }
      __syncthreads();
      if (tid == 0) atomicAdd(p.gc + (size_t)b * 32, 1u);
      // 6) frame(t-1) for batch b while the group converges
      if (t > 0) frame_group(p, t - 1, b, k, wv, lane, tid, Xf);
      // 7) group sync: wait all 8 slices of batch b
      if (tid == 0) {
        while (__hip_atomic_load(p.gc + (size_t)b * 32, __ATOMIC_RELAXED,
                                 __HIP_MEMORY_SCOPE_AGENT) < 8u * (unsigned)(t + 1))
          __builtin_amdgcn_s_sleep(1);
      }
      __syncthreads();
      // 8) read full energies, mask
      const int len = p.lens[b];
      if (tid < 200) {
        float e = ldc_f32(p.eps + (size_t)b * 256 + tid);
        e_w[tid] = (tid < len) ? e : -1.0e9f;
      }
      __syncthreads();
      // 9) softmax over 200 (redundant per block)
      float lm = (tid < 200) ? e_w[tid] : -3.0e38f;
      for (int o = 32; o > 0; o >>= 1) lm = fmaxf(lm, __shfl_down(lm, o, 64));
      if (lane == 0) red[wv] = lm;
      __syncthreads();
      float gm = red[0];
      #pragma unroll
      for (int i = 1; i < 8; ++i) gm = fmaxf(gm, red[i]);
      float ls = 0.f;
      float myp = 0.f;
      if (tid < 200) { myp = __expf(e_w[tid] - gm); ls = myp; }
      __syncthreads();
      if (tid < 200) e_w[tid] = myp;
      for (int o = 32; o > 0; o >>= 1) ls += __shfl_down(ls, o, 64);
      if (lane == 0) red[wv] = ls;
      __syncthreads();
      float inv = 0.f;
      #pragma unroll
      for (int i = 0; i < 8; ++i) inv += red[i];
      inv = 1.0f / inv;
      __syncthreads();
      if (tid < 200) {
        float wval = e_w[tid] * inv;
        e_w[tid] = wval;
        sp[15 + tid] = wval;
        scm[15 + tid] += wval;
        if (k == 0)
          p.out[ALIGN_OFF + ((size_t)b * TDEC + t) * TENC + tid] = wval;
      }
      __syncthreads();
      // 10) context slice: cols [64k, 64k+64), tt-slice [25*wv, 25*wv+25)
      {
        const int c = (k << 6) + lane;
        const float* ebase = p.enc + ((size_t)b * TENC + (size_t)(wv * 25)) * E + c;
        const float* ew = e_w + wv * 25;
        float a0 = 0.f, a1 = 0.f, a2 = 0.f, a3 = 0.f, a4 = 0.f;
        #pragma unroll
        for (int i = 0; i < 25; i += 5) {
          a0 += ew[i]     * ebase[(size_t)i * E];
          a1 += ew[i + 1] * ebase[(size_t)(i + 1) * E];
          a2 += ew[i + 2] * ebase[(size_t)(i + 2) * E];
          a3 += ew[i + 3] * ebase[(size_t)(i + 3) * E];
          a4 += ew[i + 4] * ebase[(size_t)(i + 4) * E];
        }
        cpart[(wv << 6) + lane] = ((a0 + a1) + (a2 + a3)) + a4;
      }
      __syncthreads();
      if (tid < 64) {
        float ssum = 0.f;
        #pragma unroll
        for (int s2 = 0; s2 < 8; ++s2) ssum += cpart[(s2 << 6) + tid];
        csum[tid] = ssum;
      }
      __syncthreads();
      if (tid < 16) {
        float4v v = { csum[tid * 4], csum[tid * 4 + 1], csum[tid * 4 + 2], csum[tid * 4 + 3] };
        stc_16B(p.ctxf + (size_t)(t & 1) * (E * B) + (size_t)b * 512
                + (size_t)(k << 6) + (size_t)tid * 4, v);
      }
      if (tid < 8) {
        const int q = 2 * k + (tid >> 2), lh = tid & 3;
        const int cb = tid * 8;
        unsigned w0 = (unsigned)f2bf(csum[cb])     | ((unsigned)f2bf(csum[cb + 1]) << 16);
        unsigned w1 = (unsigned)f2bf(csum[cb + 2]) | ((unsigned)f2bf(csum[cb + 3]) << 16);
        unsigned w2 = (unsigned)f2bf(csum[cb + 4]) | ((unsigned)f2bf(csum[cb + 5]) << 16);
        unsigned w3 = (unsigned)f2bf(csum[cb + 6]) | ((unsigned)f2bf(csum[cb + 7]) << 16);
        float4v pk;
        pk[0] = __builtin_bit_cast(float, w0);
        pk[1] = __builtin_bit_cast(float, w1);
        pk[2] = __builtin_bit_cast(float, w2);
        pk[3] = __builtin_bit_cast(float, w3);
        stc_16B(p.ctxb + (size_t)q * 1024 + (size_t)(b >> 4) * 512
                + (size_t)(lh * 16 + (b & 15)) * 8, pk);
      }
      // 11) issue PG fragment loads (stream overlaps barrier + PG head)
      ISSUE18();
    }
    gbar(p.bars, ++ep);

    // ---- PG: gen gates t + att gates t+1 (all 256 blocks) ----
    {
      const u16* _ct = p.ctxb + offCF;
      float4v c0, c1, c2, c3;
      LDC(c0, _ct); LDC(c1, _ct + 1024); LDC(c2, _ct + 2048); LDC(c3, _ct + 3072);
      // fragments first (ctx still in flight)
      asm volatile("s_waitcnt vmcnt(4)"
        : "+v"(e0),"+v"(e1),"+v"(e2),"+v"(e3),"+v"(e4),"+v"(e5),"+v"(e6),"+v"(e7),
          "+v"(e8),"+v"(e9),"+v"(e10),"+v"(e11),"+v"(e12),"+v"(e13),"+v"(e14),"+v"(e15),
          "+v"(e16),"+v"(e17)
        :: "memory");
      float4v accA = {0.f, 0.f, 0.f, 0.f};
      float4v accG = {0.f, 0.f, 0.f, 0.f};
      MFA(0, e0);  MFA(1, e1);
      MFA(2, e2);  MFG(0, e2);
      MFA(3, e3);  MFG(1, e3);
      MFA(4, e4);  MFG(2, e4);
      MFA(5, e5);  MFG(3, e5);
      MFA(6, e6);  MFG(4, e6);
      MFA(7, e7);  MFG(5, e7);
      MFA(8, e8);  MFG(6, e8);
      MFA(9, e9);  MFG(7, e9);
      MFG(8, e10); MFG(9, e11); MFG(10, e12); MFG(11, e13);
      MFG(12, e14); MFG(13, e15); MFG(14, e16); MFG(15, e17);
      __builtin_amdgcn_sched_barrier(0);
      asm volatile("s_waitcnt vmcnt(0)"
        : "+v"(c0),"+v"(c1),"+v"(c2),"+v"(c3) :: "memory");
      MFA(10, c0); MFG(16, c0);
      MFA(11, c1); MFG(17, c1);
      MFA(12, c2); MFG(18, c2);
      MFA(13, c3); MFG(19, c3);
      float* rA = sc + ((((0 * 2 + mt) * 4 + kqi) * 64 + lane) << 2);
      rA[0] = accA[0]; rA[1] = accA[1]; rA[2] = accA[2]; rA[3] = accA[3];
      float* rG = sc + ((((1 * 2 + mt) * 4 + kqi) * 64 + lane) << 2);
      rG[0] = accG[0]; rG[1] = accG[1]; rG[2] = accG[2]; rG[3] = accG[3];
      __syncthreads();
      if (tid < 256) {
        const int gg = tid >> 7, dj_l = (tid >> 5) & 3, mm = tid & 31;
        if (gg == 1 || doatt) {
          const int dj = blk * 4 + dj_l;
          const int mt2 = mm >> 4, m2 = mm & 15;
          const float* bias = (gg == 0) ? p.att_b : p.gen_b;
          float g4[4];
          #pragma unroll
          for (int gate = 0; gate < 4; ++gate) {
            int ln = ((m2 >> 2) << 4) | (dj_l * 4 + gate);
            int rg = m2 & 3;
            float s = 0.f;
            #pragma unroll
            for (int kk = 0; kk < 4; ++kk)
              s += sc[((((gg * 2 + mt2) * 4 + kk) * 64 + ln) << 2) + rg];
            g4[gate] = s + bias[gate * D + dj];
          }
          float* cl2 = (gg == 0) ? cAl : cGl;
          float c  = cl2[dj_l * 32 + mm];
          float cn = sigmoidf(g4[1]) * c + sigmoidf(g4[0]) * tanhfast(g4[2]);
          float hn = sigmoidf(g4[3]) * tanhfast(cn);
          cl2[dj_l * 32 + mm] = cn;
          hstg[tid] = hn;
        }
      }
      __syncthreads();
      // packed fragment-major stores: 64 threads, 8B/16B transactions
      if (tid < 64) {
        const int gg = tid >> 5, mm = tid & 31;
        const size_t offP = (size_t)(kqiB * 8 + rB) * 1024 + (size_t)(mm >> 4) * 512
                          + (size_t)(lhB * 16 + (mm & 15)) * 8 + j0B;
        if (gg == 0) {
          if (doatt) {
            unsigned w0 = (unsigned)f2bf(hstg[mm])      | ((unsigned)f2bf(hstg[32 + mm]) << 16);
            unsigned w1 = (unsigned)f2bf(hstg[64 + mm]) | ((unsigned)f2bf(hstg[96 + mm]) << 16);
            uint2v pk = {w0, w1};
            stc_8B(hAnxt + offP, pk);
          }
        } else {
          float f0 = hstg[128 + mm], f1 = hstg[160 + mm];
          float f2 = hstg[192 + mm], f3 = hstg[224 + mm];
          unsigned w0 = (unsigned)f2bf(f0) | ((unsigned)f2bf(f1) << 16);
          unsigned w1 = (unsigned)f2bf(f2) | ((unsigned)f2bf(f3) << 16);
          uint2v pk = {w0, w1};
          stc_8B(hGcur + offP, pk);
          float4v pf = {f0, f1, f2, f3};
          stc_16B(p.hGf + (size_t)mm * 1024 + blk * 4, pf);
        }
      }
    }
    gbar(p.bars, ++ep);
  }

  // ---- final frame (ft = 599), group-distributed ----
  frame_group(p, TDEC - 1, b, k, wv, lane, tid, Xf);
}

// ---------------------------------------------------------------------------
// Prenet -> preB fragment-major per t
__global__ __launch_bounds__(256) void prenet_kernel(
    const float* __restrict__ target, const float* __restrict__ W1, const float* __restrict__ b1,
    const float* __restrict__ W2, const float* __restrict__ b2, u16* __restrict__ preB)
{
  const int t = blockIdx.x;
  const int tid = threadIdx.x;
  __shared__ float tg[B][M];
  __shared__ float x1[B][P];
  for (int i = tid; i < B * M; i += 256) {
    int b = i / M, m = i - b * M;
    tg[b][m] = (t == 0) ? 0.0f : target[(size_t)b * M * TDEC + (size_t)m * TDEC + (t - 1)];
  }
  __syncthreads();
  for (int i = tid; i < B * P; i += 256) {
    int b = i >> 8, j = i & 255;
    const float* w = W1 + (size_t)j * M;
    float acc = b1[j];
    for (int m = 0; m < M; ++m) acc += w[m] * tg[b][m];
    x1[b][j] = fmaxf(acc, 0.0f);
  }
  __syncthreads();
  for (int i = tid; i < B * P; i += 256) {
    int b = i >> 8, j = i & 255;
    const float* w = W2 + (size_t)j * P;
    float acc = b2[j];
    for (int m = 0; m < P; m += 4)
      acc += w[m]*x1[b][m] + w[m+1]*x1[b][m+1] + w[m+2]*x1[b][m+2] + w[m+3]*x1[b][m+3];
    int kqi = j >> 6, r = (j >> 5) & 1, lh = (j >> 3) & 3, jj = j & 7;
    size_t off = (size_t)(kqi * 2 + r) * 1024 + (size_t)(b >> 4) * 512
               + (size_t)(lh * 16 + (b & 15)) * 8 + jj;
    preB[(size_t)t * (B * P) + off] = f2bf(fmaxf(acc, 0.0f));
  }
}

// ---------------------------------------------------------------------------
__global__ __launch_bounds__(256) void procmem_kernel(
    const float* __restrict__ enc, const float* __restrict__ Wm, float* __restrict__ pm)
{
  const int blk = blockIdx.x;
  const int b = blk >> 3;
  const int t0 = (blk & 7) * 25;
  for (int i = threadIdx.x; i < 25 * A; i += 256) {
    int tl = i >> 7, a = i & 127;
    int t = t0 + tl;
    const float* x = enc + ((size_t)b * TENC + t) * E;
    const float* w = Wm + (size_t)a * E;
    float acc = 0.0f;
    for (int k = 0; k < E; k += 4)
      acc += w[k]*x[k] + w[k+1]*x[k+1] + w[k+2]*x[k+2] + w[k+3]*x[k+3];
    pm[((size_t)b * TENC + t) * A + a] = acc;
  }
}

// ---------------------------------------------------------------------------
__global__ __launch_bounds__(256) void kpk_kernel(
    const float* __restrict__ lker, const float* __restrict__ Wloc, u16* __restrict__ kpk)
{
  int idx = blockIdx.x * 256 + threadIdx.x;
  if (idx >= 8192) return;
  int j = idx & 7, ln = (idx >> 3) & 63, tn = (idx >> 9) & 7, pass = idx >> 12;
  int a = tn * 16 + (ln & 15);
  int k = ((ln >> 4) << 3) + j;
  float v = 0.f;
  if (k < KC) {
    for (int f = 0; f < LF; ++f)
      v += Wloc[a * LF + f] * lker[f * (2 * KC) + pass * KC + k];
  }
  kpk[idx] = f2bf(v);
}

// ---------------------------------------------------------------------------
__global__ __launch_bounds__(256) void wqpack_kernel(
    const float* __restrict__ Wq, u16* __restrict__ wqb)
{
  int idx = blockIdx.x * 256 + threadIdx.x;
  if (idx < A * D) wqb[idx] = f2bf(Wq[idx]);
}

// ---------------------------------------------------------------------------
// fwb[j][k]: j=0..79 frame rows, j=80 stop row; bf16
__global__ __launch_bounds__(256) void fwpack_kernel(
    const float* __restrict__ frame_W, const float* __restrict__ stop_W, u16* __restrict__ fwb)
{
  int idx = blockIdx.x * 256 + threadIdx.x;
  if (idx >= 81 * 1536) return;
  int j = idx / 1536, k = idx - j * 1536;
  float v = (j < M) ? frame_W[(size_t)j * 1536 + k] : stop_W[k];
  fwb[idx] = f2bf(v);
}

// ---------------------------------------------------------------------------
extern "C" void kernel_launch(void* const* d_in, const int* in_sizes, int n_in,
                              void* d_out, int out_size, void* d_ws, size_t ws_size,
                              hipStream_t stream)
{
  const float* enc      = (const float*)d_in[0];
  const int*   lens     = (const int*)  d_in[1];
  const float* target   = (const float*)d_in[2];
  const float* pW1      = (const float*)d_in[4];
  const float* pb1      = (const float*)d_in[5];
  const float* pW2      = (const float*)d_in[6];
  const float* pb2      = (const float*)d_in[7];
  const float* att_Wih  = (const float*)d_in[8];
  const float* att_Whh  = (const float*)d_in[9];
  const float* att_b    = (const float*)d_in[10];
  const float* gen_Wih  = (const float*)d_in[11];
  const float* gen_Whh  = (const float*)d_in[12];
  const float* gen_b    = (const float*)d_in[13];
  const float* Wq       = (const float*)d_in[14];
  const float* Wm       = (const float*)d_in[15];
  const float* lker     = (const float*)d_in[16];
  const float* Wloc     = (const float*)d_in[17];
  const float* v_att    = (const float*)d_in[18];
  const float* b_att    = (const float*)d_in[19];
  const float* frame_W  = (const float*)d_in[20];
  const float* frame_b  = (const float*)d_in[21];
  const float* stop_W   = (const float*)d_in[22];
  const float* stop_b   = (const float*)d_in[23];

  float* ws = (float*)d_ws;
  float* st = ws + OFF_ST;

  Params p;
  p.enc = enc; p.lens = lens;
  p.att_Wih = att_Wih; p.att_Whh = att_Whh; p.att_b = att_b;
  p.gen_Wih = gen_Wih; p.gen_Whh = gen_Whh; p.gen_b = gen_b;
  p.v_att = v_att; p.b_att = b_att;
  p.frame_b = frame_b; p.stop_b = stop_b;
  p.pm   = ws + OFF_PM;
  p.preB = (const u16*)(ws + OFF_PREB);
  p.kpk  = (const u16*)(ws + OFF_KPK);
  p.wqb  = (const u16*)(ws + OFF_WQB);
  p.fwb  = (const u16*)(ws + OFF_FWB);
  p.hAb0 = (u16*)(st + ST_HAB0);
  p.hAb1 = (u16*)(st + ST_HAB1);
  p.hGb0 = (u16*)(st + ST_HGB0);
  p.hGb1 = (u16*)(st + ST_HGB1);
  p.ctxb = (u16*)(st + ST_CTXB);
  p.ctxf = st + ST_CTXF;
  p.hGf  = st + ST_HGF;
  p.bars = (unsigned*)(st + ST_BARS);
  p.eps  = st + ST_EPS;
  p.gc   = (unsigned*)(st + ST_GC);
  p.out  = (float*)d_out;

  hipMemsetAsync((void*)st, 0, N_STATE * sizeof(float), stream);

  kpk_kernel    <<<32, 256, 0, stream>>>(lker, Wloc, (u16*)(ws + OFF_KPK));
  wqpack_kernel <<<512, 256, 0, stream>>>(Wq, (u16*)(ws + OFF_WQB));
  fwpack_kernel <<<486, 256, 0, stream>>>(frame_W, stop_W, (u16*)(ws + OFF_FWB));
  prenet_kernel <<<TDEC, 256, 0, stream>>>(target, pW1, pb1, pW2, pb2, (u16*)(ws + OFF_PREB));
  procmem_kernel<<<256, 256, 0, stream>>>(enc, Wm, ws + OFF_PM);

  hipFuncSetAttribute((const void*)persist_kernel,
                      hipFuncAttributeMaxDynamicSharedMemorySize, SMEM_BYTES);
  persist_kernel<<<256, 512, SMEM_BYTES, stream>>>(p);
}